// Round 16
// baseline (251.049 us; speedup 1.0000x reference)
//
#include <hip/hip_runtime.h>
#include <hip/hip_bf16.h>

namespace {
constexpr int S  = 4096;
constexpr int D  = 768;
constexpr int H  = 12;
constexpr int N3 = 2304;   // 3*D

typedef __bf16 bf16x4 __attribute__((ext_vector_type(4)));
typedef __bf16 bf16x8 __attribute__((ext_vector_type(8)));
typedef float  floatx4 __attribute__((ext_vector_type(4)));

// async global->LDS, 16B per lane; LDS dest = wave-uniform base + lane*16.
__device__ inline void glds16(const __bf16* g, __bf16* l) {
  __builtin_amdgcn_global_load_lds(
      (const __attribute__((address_space(1))) void*)(const void*)g,
      (__attribute__((address_space(3))) void*)(void*)l, 16, 0, 0);
}

// ---------------------------------------------------------------------------
// Kernel 0a: x (fp32) -> xb (bf16).
// ---------------------------------------------------------------------------
__global__ __launch_bounds__(256)
void convert_x(const float* __restrict__ x, __bf16* __restrict__ xb)
{
  const int i = (blockIdx.x * 256 + threadIdx.x) * 4;
  floatx4 v = *reinterpret_cast<const floatx4*>(x + i);
  bf16x4 b;
  #pragma unroll
  for (int e = 0; e < 4; ++e) b[e] = (__bf16)v[e];
  *reinterpret_cast<bf16x4*>(xb + i) = b;
}

// ---------------------------------------------------------------------------
// Kernel 0b: W (fp32, [768][2304]) -> WT (bf16, [2304][768]).
// ---------------------------------------------------------------------------
__global__ __launch_bounds__(256)
void convert_wt(const float* __restrict__ W, __bf16* __restrict__ WT)
{
  __shared__ float T[64][65];
  const int tid = threadIdx.x;
  const int d0 = blockIdx.x * 64, e0 = blockIdx.y * 64;
  const int rr = tid >> 4, c4 = (tid & 15) * 4;
  #pragma unroll
  for (int it = 0; it < 4; ++it) {
    int d = it * 16 + rr;
    floatx4 v = *reinterpret_cast<const floatx4*>(W + (d0 + d) * N3 + e0 + c4);
    #pragma unroll
    for (int e = 0; e < 4; ++e) T[d][c4 + e] = v[e];
  }
  __syncthreads();
  #pragma unroll
  for (int it = 0; it < 4; ++it) {
    int e = it * 16 + rr;
    bf16x4 b;
    #pragma unroll
    for (int i = 0; i < 4; ++i) b[i] = (__bf16)T[c4 + i][e];
    *reinterpret_cast<bf16x4*>(WT + (e0 + e) * D + d0 + c4) = b;
  }
}

// ---------------------------------------------------------------------------
// Kernel 1 (UNCHANGED from R15 — controlled variable; expect its true dur to
// surface in top-5 this round): QKV GEMM, bf16, 128x128 tile, BK=64,
// global_load_lds + XOR swizzle. Epilogue: Q,K row-major; V^T k-slot-permuted.
// ---------------------------------------------------------------------------
__global__ __launch_bounds__(256)
void qkv_gemm(const __bf16* __restrict__ xb, const __bf16* __restrict__ WT,
              const float* __restrict__ bq, __bf16* __restrict__ Qb,
              __bf16* __restrict__ Kb, __bf16* __restrict__ vT)
{
  __shared__ __bf16 As[128 * 64];
  __shared__ __bf16 Bs[128 * 64];

  const int tid  = threadIdx.x;
  const int wave = tid >> 6, lane = tid & 63;
  const int quad = lane >> 4, l16 = lane & 15;
  const int m_base = (wave >> 1) * 64;
  const int n_base = (wave & 1) * 64;
  const int bm = blockIdx.x, bn = blockIdx.y;
  const int srow = lane >> 3, sg = lane & 7;

  floatx4 acc[4][4];
  #pragma unroll
  for (int i = 0; i < 4; ++i)
    #pragma unroll
    for (int j = 0; j < 4; ++j) acc[i][j] = (floatx4){0.f, 0.f, 0.f, 0.f};

  for (int ks = 0; ks < 12; ++ks) {
    const int k0 = ks * 64;
    __syncthreads();
    #pragma unroll
    for (int it = 0; it < 4; ++it) {
      int rbase = it * 32 + wave * 8;
      int row = rbase + srow;
      int g = sg ^ (row & 7);
      glds16(xb + (size_t)(bm * 128 + row) * D + k0 + g * 8, As + rbase * 64);
      glds16(WT + (size_t)(bn * 128 + row) * D + k0 + g * 8, Bs + rbase * 64);
    }
    __syncthreads();

    bf16x8 af[4][2], bfr[4][2];
    #pragma unroll
    for (int mt = 0; mt < 4; ++mt)
      #pragma unroll
      for (int kt = 0; kt < 2; ++kt) {
        int m = m_base + mt * 16 + l16;
        af[mt][kt] = *reinterpret_cast<const bf16x8*>(
            &As[m * 64 + ((((kt << 2) | quad) ^ (l16 & 7)) << 3)]);
      }
    #pragma unroll
    for (int nt = 0; nt < 4; ++nt)
      #pragma unroll
      for (int kt = 0; kt < 2; ++kt) {
        int n = n_base + nt * 16 + l16;
        bfr[nt][kt] = *reinterpret_cast<const bf16x8*>(
            &Bs[n * 64 + ((((kt << 2) | quad) ^ (l16 & 7)) << 3)]);
      }
    #pragma unroll
    for (int kt = 0; kt < 2; ++kt)
      #pragma unroll
      for (int mt = 0; mt < 4; ++mt)
        #pragma unroll
        for (int nt = 0; nt < 4; ++nt)
          acc[mt][nt] = __builtin_amdgcn_mfma_f32_16x16x32_bf16(
              af[mt][kt], bfr[nt][kt], acc[mt][nt], 0, 0, 0);
  }

  #pragma unroll
  for (int nt = 0; nt < 4; ++nt) {
    int col = bn * 128 + n_base + nt * 16 + l16;
    float bias = bq[col];
    #pragma unroll
    for (int mt = 0; mt < 4; ++mt) {
      int row = bm * 128 + m_base + mt * 16 + quad * 4;
      #pragma unroll
      for (int r = 0; r < 4; ++r) {
        __bf16 v = (__bf16)(acc[mt][nt][r] + bias);
        if (bn < 6)       Qb[(row + r) * D + col] = v;
        else if (bn < 12) Kb[(row + r) * D + (col - D)] = v;
        else {
          int t = row + r;
          int pos = (t & ~31) | (quad << 3) | (t & 16) / 4 | r;
          vT[(size_t)(col - 2 * D) * S + pos] = v;
        }
      }
    }
  }
}

// ---------------------------------------------------------------------------
// Kernel 2: flash attention. NEW work split: each wave covers ALL 64 q x a
// 32-t quarter (th in 0..3) -> K-frag reads serve 4 q-tiles (8 b128/wave/step
// total vs 20). Both K and V staged via global_load_lds + XOR swizzle: zero
// ds_writes in the loop. exp2f softmax (de-chained). 4-way tree reduction of
// O^T/l at the end (LDS union).
// ---------------------------------------------------------------------------
__global__ __launch_bounds__(256)
void attention(const __bf16* __restrict__ Qb, const __bf16* __restrict__ Kb,
               const __bf16* __restrict__ vT, const float* __restrict__ mask,
               float* __restrict__ out)
{
  __shared__ char smem[36864];
  __bf16* Ks = (__bf16*)smem;                 // [128][64]  swizzled, 16 KB
  __bf16* Vt = (__bf16*)(smem + 16384);       // [64][128]  swizzled+permuted, 16 KB
  float*  Lo0 = (float*)smem;                 // 64x68 fp32 (reduction, aliased)
  float*  Lo1 = (float*)(smem + 17408);
  float*  Ll  = (float*)(smem + 34816);       // 4 x 64 l-partials

  const int tid  = threadIdx.x;
  const int wave = tid >> 6, lane = tid & 63;
  const int quad = lane >> 4, l16 = lane & 15;
  const int th = wave;                        // t-quarter 32 per 128-step
  const int qb = blockIdx.x, h = blockIdx.y;
  const int q0 = qb * 64;
  const int qcol = h * 64;
  const int srow = lane >> 3, sg = lane & 7;
  const int vrow = lane >> 4, vs = lane & 15;
  constexpr float C2 = 14426.950408889634f;   // 10000*log2(e)

  // Q fragments (B-operand of S^T): all 64 q rows.
  bf16x8 qf[4][2];
  #pragma unroll
  for (int nt = 0; nt < 4; ++nt)
    #pragma unroll
    for (int kt = 0; kt < 2; ++kt)
      qf[nt][kt] = *reinterpret_cast<const bf16x8*>(
          Qb + (q0 + nt * 16 + l16) * D + qcol + kt * 32 + quad * 8);

  floatx4 accO[4][4];   // [wt][nt]: w=wt*16+quad*4+r, q=nt*16+l16
  #pragma unroll
  for (int wt = 0; wt < 4; ++wt)
    #pragma unroll
    for (int nt = 0; nt < 4; ++nt) accO[wt][nt] = (floatx4){0.f, 0.f, 0.f, 0.f};
  float l_lane[4] = {0.f, 0.f, 0.f, 0.f};

  for (int j = 0; j < 32; ++j) {
    __syncthreads();
    // K tile 128x64 (16 KB) + V tile 64x128 (16 KB), all via async DMA.
    #pragma unroll
    for (int it = 0; it < 4; ++it) {
      int rbase = it * 32 + wave * 8;
      int t = rbase + srow;
      glds16(Kb + (size_t)(j * 128 + t) * D + qcol + (sg ^ (t & 7)) * 8,
             Ks + rbase * 64);
      int wbase = it * 16 + wave * 4;
      int w = wbase + vrow;
      glds16(vT + (size_t)(qcol + w) * S + j * 128 + (vs ^ (w & 7)) * 8,
             Vt + wbase * 128);
    }
    __syncthreads();

    // S^T = K Q^T over this wave's 2 t-tiles x 4 q-tiles; exp2 in-register.
    bf16x4 ps[2][4];
    #pragma unroll
    for (int mt = 0; mt < 2; ++mt) {
      int t = th * 32 + mt * 16 + l16;
      bf16x8 kf[2];
      #pragma unroll
      for (int kt = 0; kt < 2; ++kt)
        kf[kt] = *reinterpret_cast<const bf16x8*>(
            &Ks[t * 64 + ((((kt << 2) | quad) ^ (l16 & 7)) << 3)]);
      floatx4 mv = *reinterpret_cast<const floatx4*>(
          mask + j * 128 + th * 32 + mt * 16 + quad * 4);
      floatx4 mb;
      #pragma unroll
      for (int r = 0; r < 4; ++r) mb[r] = (mv[r] - 1.f) * C2;
      #pragma unroll
      for (int nt = 0; nt < 4; ++nt) {
        floatx4 s = (floatx4){0.f, 0.f, 0.f, 0.f};
        #pragma unroll
        for (int kt = 0; kt < 2; ++kt)
          s = __builtin_amdgcn_mfma_f32_16x16x32_bf16(kf[kt], qf[nt][kt], s, 0, 0, 0);
        #pragma unroll
        for (int r = 0; r < 4; ++r) {
          float p = exp2f(fmaf(s[r], 0.1803368801111244f, mb[r]));
          l_lane[nt] += p;
          ps[mt][nt][r] = (__bf16)p;
        }
      }
    }

    // O^T += V^T P^T (wave's 32-t slice = one k-group).
    bf16x8 pf[4];
    #pragma unroll
    for (int nt = 0; nt < 4; ++nt)
      #pragma unroll
      for (int r = 0; r < 4; ++r) {
        pf[nt][r]     = ps[0][nt][r];
        pf[nt][4 + r] = ps[1][nt][r];
      }
    #pragma unroll
    for (int wt = 0; wt < 4; ++wt) {
      int w = wt * 16 + l16;
      bf16x8 vf = *reinterpret_cast<const bf16x8*>(
          &Vt[w * 128 + (((th * 4 + quad) ^ (w & 7)) << 3)]);
      #pragma unroll
      for (int nt = 0; nt < 4; ++nt)
        accO[wt][nt] = __builtin_amdgcn_mfma_f32_16x16x32_bf16(
            vf, pf[nt], accO[wt][nt], 0, 0, 0);
    }
  }

  // ---- 4-way tree reduction over t-quarters ----
  #pragma unroll
  for (int nt = 0; nt < 4; ++nt) {
    l_lane[nt] += __shfl_xor(l_lane[nt], 16, 64);
    l_lane[nt] += __shfl_xor(l_lane[nt], 32, 64);
  }
  __syncthreads();   // all Ks/Vt reads done; alias Lo0/Lo1
  if (wave >= 2) {
    float* dst = (wave == 2) ? Lo0 : Lo1;
    #pragma unroll
    for (int wt = 0; wt < 4; ++wt)
      #pragma unroll
      for (int nt = 0; nt < 4; ++nt)
        #pragma unroll
        for (int r = 0; r < 4; ++r)
          dst[(wt * 16 + quad * 4 + r) * 68 + nt * 16 + l16] = accO[wt][nt][r];
  }
  if (quad == 0)
    #pragma unroll
    for (int nt = 0; nt < 4; ++nt)
      Ll[wave * 64 + nt * 16 + l16] = l_lane[nt];
  __syncthreads();
  if (wave < 2) {
    const float* src = (wave == 0) ? Lo0 : Lo1;
    #pragma unroll
    for (int wt = 0; wt < 4; ++wt)
      #pragma unroll
      for (int nt = 0; nt < 4; ++nt)
        #pragma unroll
        for (int r = 0; r < 4; ++r)
          accO[wt][nt][r] += src[(wt * 16 + quad * 4 + r) * 68 + nt * 16 + l16];
  }
  __syncthreads();
  if (wave == 1) {
    #pragma unroll
    for (int wt = 0; wt < 4; ++wt)
      #pragma unroll
      for (int nt = 0; nt < 4; ++nt)
        #pragma unroll
        for (int r = 0; r < 4; ++r)
          Lo0[(wt * 16 + quad * 4 + r) * 68 + nt * 16 + l16] = accO[wt][nt][r];
  }
  __syncthreads();
  if (wave == 0) {
    float l_tot[4];
    #pragma unroll
    for (int nt = 0; nt < 4; ++nt) {
      int q = nt * 16 + l16;
      l_tot[nt] = Ll[q] + Ll[64 + q] + Ll[128 + q] + Ll[192 + q];
    }
    #pragma unroll
    for (int wt = 0; wt < 4; ++wt)
      #pragma unroll
      for (int nt = 0; nt < 4; ++nt) {
        int q = nt * 16 + l16;
        floatx4 o;
        #pragma unroll
        for (int r = 0; r < 4; ++r)
          o[r] = (accO[wt][nt][r] +
                  Lo0[(wt * 16 + quad * 4 + r) * 68 + q]) / l_tot[nt];
        *reinterpret_cast<floatx4*>(
            &out[(q0 + q) * D + qcol + wt * 16 + quad * 4]) = o;
      }
  }
}

} // namespace

extern "C" void kernel_launch(void* const* d_in, const int* in_sizes, int n_in,
                              void* d_out, int out_size, void* d_ws, size_t ws_size,
                              hipStream_t stream) {
  const float *x = nullptr, *mask = nullptr, *Wq = nullptr, *bq = nullptr;
  for (int i = 0; i < n_in; ++i) {
    switch (in_sizes[i]) {
      case 3145728: x    = (const float*)d_in[i]; break;
      case 4096:    mask = (const float*)d_in[i]; break;
      case 1769472: Wq   = (const float*)d_in[i]; break;
      case 2304:    bq   = (const float*)d_in[i]; break;
      default: break;
    }
  }

  __bf16* xb = (__bf16*)d_out;               // bf16 scratch in d_out
  __bf16* WT = xb + (size_t)S * D;
  __bf16* Qb = (__bf16*)d_ws;
  __bf16* Kb = Qb + (size_t)S * D;
  __bf16* vT = Kb + (size_t)S * D;

  convert_x <<<(S * D) / 1024, 256, 0, stream>>>(x, xb);
  convert_wt<<<dim3(D / 64, N3 / 64), 256, 0, stream>>>(Wq, WT);
  qkv_gemm  <<<dim3(S / 128, N3 / 128), 256, 0, stream>>>(xb, WT, bq, Qb, Kb, vT);
  attention <<<dim3(S / 64, H), 256, 0, stream>>>(Qb, Kb, vT, mask, (float*)d_out);
}

// Round 17
// 208.656 us; speedup vs baseline: 1.2032x; 1.2032x over previous
//
#include <hip/hip_runtime.h>
#include <hip/hip_bf16.h>

namespace {
constexpr int S  = 4096;
constexpr int D  = 768;
constexpr int H  = 12;
constexpr int N3 = 2304;   // 3*D

typedef __bf16 bf16x4 __attribute__((ext_vector_type(4)));
typedef __bf16 bf16x8 __attribute__((ext_vector_type(8)));
typedef float  floatx4 __attribute__((ext_vector_type(4)));

// async global->LDS, 16B per lane; LDS dest = wave-uniform base + lane*16.
__device__ inline void glds16(const __bf16* g, __bf16* l) {
  __builtin_amdgcn_global_load_lds(
      (const __attribute__((address_space(1))) void*)(const void*)g,
      (__attribute__((address_space(3))) void*)(void*)l, 16, 0, 0);
}

// ---------------------------------------------------------------------------
// Kernel 0a: x (fp32) -> xb (bf16).
// ---------------------------------------------------------------------------
__global__ __launch_bounds__(256)
void convert_x(const float* __restrict__ x, __bf16* __restrict__ xb)
{
  const int i = (blockIdx.x * 256 + threadIdx.x) * 4;
  floatx4 v = *reinterpret_cast<const floatx4*>(x + i);
  bf16x4 b;
  #pragma unroll
  for (int e = 0; e < 4; ++e) b[e] = (__bf16)v[e];
  *reinterpret_cast<bf16x4*>(xb + i) = b;
}

// ---------------------------------------------------------------------------
// Kernel 0b: W (fp32, [768][2304]) -> WT (bf16, [2304][768]).
// ---------------------------------------------------------------------------
__global__ __launch_bounds__(256)
void convert_wt(const float* __restrict__ W, __bf16* __restrict__ WT)
{
  __shared__ float T[64][65];
  const int tid = threadIdx.x;
  const int d0 = blockIdx.x * 64, e0 = blockIdx.y * 64;
  const int rr = tid >> 4, c4 = (tid & 15) * 4;
  #pragma unroll
  for (int it = 0; it < 4; ++it) {
    int d = it * 16 + rr;
    floatx4 v = *reinterpret_cast<const floatx4*>(W + (d0 + d) * N3 + e0 + c4);
    #pragma unroll
    for (int e = 0; e < 4; ++e) T[d][c4 + e] = v[e];
  }
  __syncthreads();
  #pragma unroll
  for (int it = 0; it < 4; ++it) {
    int e = it * 16 + rr;
    bf16x4 b;
    #pragma unroll
    for (int i = 0; i < 4; ++i) b[i] = (__bf16)T[c4 + i][e];
    *reinterpret_cast<bf16x4*>(WT + (e0 + e) * D + d0 + c4) = b;
  }
}

// ---------------------------------------------------------------------------
// Kernel 1: QKV GEMM (R15 mainloop). NEW epilogue for V: instead of the 2B
// 64-line global scatter (each lane's col is 8KB apart in vT), acc is staged
// into a swizzled LDS tile (addr = w*128 + (pos ^ ((w&7)<<3)): scalar writes
// land 2-way max) and stored as coalesced 16B runs of vT. LDS reuses As/Bs.
// ---------------------------------------------------------------------------
__global__ __launch_bounds__(256)
void qkv_gemm(const __bf16* __restrict__ xb, const __bf16* __restrict__ WT,
              const float* __restrict__ bq, __bf16* __restrict__ Qb,
              __bf16* __restrict__ Kb, __bf16* __restrict__ vT)
{
  __shared__ __bf16 smem[16384];           // 32 KB: As | Bs, later vts
  __bf16* As = smem;                        // [128][64] swizzled
  __bf16* Bs = smem + 8192;                 // [128][64] swizzled

  const int tid  = threadIdx.x;
  const int wave = tid >> 6, lane = tid & 63;
  const int quad = lane >> 4, l16 = lane & 15;
  const int m_base = (wave >> 1) * 64;
  const int n_base = (wave & 1) * 64;
  const int bm = blockIdx.x, bn = blockIdx.y;
  const int srow = lane >> 3, sg = lane & 7;

  floatx4 acc[4][4];
  #pragma unroll
  for (int i = 0; i < 4; ++i)
    #pragma unroll
    for (int j = 0; j < 4; ++j) acc[i][j] = (floatx4){0.f, 0.f, 0.f, 0.f};

  for (int ks = 0; ks < 12; ++ks) {
    const int k0 = ks * 64;
    __syncthreads();
    #pragma unroll
    for (int it = 0; it < 4; ++it) {
      int rbase = it * 32 + wave * 8;
      int row = rbase + srow;
      int g = sg ^ (row & 7);
      glds16(xb + (size_t)(bm * 128 + row) * D + k0 + g * 8, As + rbase * 64);
      glds16(WT + (size_t)(bn * 128 + row) * D + k0 + g * 8, Bs + rbase * 64);
    }
    __syncthreads();

    bf16x8 af[4][2], bfr[4][2];
    #pragma unroll
    for (int mt = 0; mt < 4; ++mt)
      #pragma unroll
      for (int kt = 0; kt < 2; ++kt) {
        int m = m_base + mt * 16 + l16;
        af[mt][kt] = *reinterpret_cast<const bf16x8*>(
            &As[m * 64 + ((((kt << 2) | quad) ^ (l16 & 7)) << 3)]);
      }
    #pragma unroll
    for (int nt = 0; nt < 4; ++nt)
      #pragma unroll
      for (int kt = 0; kt < 2; ++kt) {
        int n = n_base + nt * 16 + l16;
        bfr[nt][kt] = *reinterpret_cast<const bf16x8*>(
            &Bs[n * 64 + ((((kt << 2) | quad) ^ (l16 & 7)) << 3)]);
      }
    #pragma unroll
    for (int kt = 0; kt < 2; ++kt)
      #pragma unroll
      for (int mt = 0; mt < 4; ++mt)
        #pragma unroll
        for (int nt = 0; nt < 4; ++nt)
          acc[mt][nt] = __builtin_amdgcn_mfma_f32_16x16x32_bf16(
              af[mt][kt], bfr[nt][kt], acc[mt][nt], 0, 0, 0);
  }

  if (bn < 12) {
    // Q/K: direct stores (4x32B segments per instr — acceptable).
    #pragma unroll
    for (int nt = 0; nt < 4; ++nt) {
      int col = bn * 128 + n_base + nt * 16 + l16;
      float bias = bq[col];
      #pragma unroll
      for (int mt = 0; mt < 4; ++mt) {
        int row = bm * 128 + m_base + mt * 16 + quad * 4;
        #pragma unroll
        for (int r = 0; r < 4; ++r) {
          __bf16 v = (__bf16)(acc[mt][nt][r] + bias);
          if (bn < 6) Qb[(row + r) * D + col] = v;
          else        Kb[(row + r) * D + (col - D)] = v;
        }
      }
    }
  } else {
    // V: LDS transpose (k-slot-permuted), then coalesced vT stores.
    __syncthreads();   // done with As/Bs
    __bf16* vts = smem;   // [w 128][t 128], addr = w*128 + (pos ^ ((w&7)<<3))
    #pragma unroll
    for (int nt = 0; nt < 4; ++nt) {
      int wl = n_base + nt * 16 + l16;
      float bias = bq[bn * 128 + wl];
      int sw = (wl & 7) << 3;
      #pragma unroll
      for (int mt = 0; mt < 4; ++mt) {
        #pragma unroll
        for (int r = 0; r < 4; ++r) {
          int tl = m_base + mt * 16 + quad * 4 + r;
          int pos = (tl & ~31) | (quad << 3) | ((tl & 16) >> 2) | r;
          vts[wl * 128 + (pos ^ sw)] = (__bf16)(acc[mt][nt][r] + bias);
        }
      }
    }
    __syncthreads();
    const int w0g = bn * 128 - 2 * D;
    #pragma unroll
    for (int it = 0; it < 8; ++it) {
      int c = it * 256 + tid;
      int wl = c >> 4, t0 = (c & 15) * 8;
      bf16x8 v = *reinterpret_cast<const bf16x8*>(
          &vts[wl * 128 + (t0 ^ ((wl & 7) << 3))]);
      *reinterpret_cast<bf16x8*>(
          &vT[(size_t)(w0g + wl) * S + bm * 128 + t0]) = v;
    }
  }
}

// ---------------------------------------------------------------------------
// Kernel 2 (VERBATIM R15, measured 113.5 us): flash attention,
// P-in-registers, wave = 32q x 64t, K via global_load_lds + XOR swizzle,
// V fragments single b128 from k-slot-permuted vT.
// ---------------------------------------------------------------------------
__global__ __launch_bounds__(256)
void attention(const __bf16* __restrict__ Qb, const __bf16* __restrict__ Kb,
               const __bf16* __restrict__ vT, const float* __restrict__ mask,
               float* __restrict__ out)
{
  __shared__ char smem[16384 + 17408 + 256];
  __bf16* Ks = (__bf16*)smem;                        // [128][64], swizzled
  __bf16* Vt = (__bf16*)(smem + 16384);              // [64][136], permuted-t
  float*  Ll = (float*)(smem + 16384 + 17408);       // l partials (64 floats)
  float*  Lo = (float*)smem;                         // alias, end-reduction only

  const int tid  = threadIdx.x;
  const int wave = tid >> 6, lane = tid & 63;
  const int quad = lane >> 4, l16 = lane & 15;
  const int qh = wave >> 1;       // q-half
  const int th = wave & 1;        // t-half
  const int qb = blockIdx.x, h = blockIdx.y;
  const int q0 = qb * 64;
  const int qcol = h * 64;
  const int srow = lane >> 3, sg = lane & 7;

  bf16x8 qf[2][2];
  #pragma unroll
  for (int nt = 0; nt < 2; ++nt)
    #pragma unroll
    for (int kt = 0; kt < 2; ++kt)
      qf[nt][kt] = *reinterpret_cast<const bf16x8*>(
          Qb + (q0 + qh * 32 + nt * 16 + l16) * D + qcol + kt * 32 + quad * 8);

  floatx4 accO[4][2];
  #pragma unroll
  for (int wt = 0; wt < 4; ++wt)
    #pragma unroll
    for (int nt = 0; nt < 2; ++nt) accO[wt][nt] = (floatx4){0.f, 0.f, 0.f, 0.f};
  float l_lane[2] = {0.f, 0.f};

  for (int j = 0; j < 32; ++j) {
    __syncthreads();
    #pragma unroll
    for (int it = 0; it < 4; ++it) {
      int rbase = it * 32 + wave * 8;
      int t = rbase + srow;
      int g = sg ^ (t & 7);
      glds16(Kb + (size_t)(j * 128 + t) * D + qcol + g * 8, Ks + rbase * 64);
    }
    #pragma unroll
    for (int it = 0; it < 4; ++it) {
      int c = it * 256 + tid;
      int w = c >> 4, t0 = (c & 15) * 8;
      *reinterpret_cast<bf16x8*>(&Vt[w * 136 + t0]) =
          *reinterpret_cast<const bf16x8*>(vT + (size_t)(qcol + w) * S + j * 128 + t0);
    }
    __syncthreads();

    // S^T = K Q^T ; P = exp(...) in-register.
    bf16x4 ps[4][2];
    #pragma unroll
    for (int mt = 0; mt < 4; ++mt) {
      int trow = th * 64 + mt * 16 + l16;
      bf16x8 kf[2];
      #pragma unroll
      for (int kt = 0; kt < 2; ++kt)
        kf[kt] = *reinterpret_cast<const bf16x8*>(
            &Ks[trow * 64 + ((((kt << 2) | quad) ^ (l16 & 7)) << 3)]);
      floatx4 mv = *reinterpret_cast<const floatx4*>(
          mask + j * 128 + th * 64 + mt * 16 + quad * 4);
      #pragma unroll
      for (int nt = 0; nt < 2; ++nt) {
        floatx4 s = (floatx4){0.f, 0.f, 0.f, 0.f};
        #pragma unroll
        for (int kt = 0; kt < 2; ++kt)
          s = __builtin_amdgcn_mfma_f32_16x16x32_bf16(kf[kt], qf[nt][kt], s, 0, 0, 0);
        #pragma unroll
        for (int r = 0; r < 4; ++r) {
          float p = __expf(s[r] * 0.125f - 10000.f * (1.f - mv[r]));
          l_lane[nt] += p;
          ps[mt][nt][r] = (__bf16)p;
        }
      }
    }

    // O^T += V^T P^T : vf ONE b128 (k-slot-permuted), pf register concat.
    #pragma unroll
    for (int u = 0; u < 2; ++u) {
      bf16x8 pf[2];
      #pragma unroll
      for (int nt = 0; nt < 2; ++nt)
        #pragma unroll
        for (int r = 0; r < 4; ++r) {
          pf[nt][r]     = ps[2 * u][nt][r];
          pf[nt][4 + r] = ps[2 * u + 1][nt][r];
        }
      #pragma unroll
      for (int wt = 0; wt < 4; ++wt) {
        bf16x8 vf = *reinterpret_cast<const bf16x8*>(
            &Vt[(wt * 16 + l16) * 136 + th * 64 + u * 32 + quad * 8]);
        #pragma unroll
        for (int nt = 0; nt < 2; ++nt)
          accO[wt][nt] = __builtin_amdgcn_mfma_f32_16x16x32_bf16(
              vf, pf[nt], accO[wt][nt], 0, 0, 0);
      }
    }
  }

  // ---- cross-wave reduction over t-halves ----
  #pragma unroll
  for (int nt = 0; nt < 2; ++nt) {
    l_lane[nt] += __shfl_xor(l_lane[nt], 16, 64);
    l_lane[nt] += __shfl_xor(l_lane[nt], 32, 64);
  }
  __syncthreads();   // all Ks/Vt reads done; safe to alias Lo
  if (th == 1) {
    float* dst = Lo + qh * (64 * 33);
    #pragma unroll
    for (int wt = 0; wt < 4; ++wt)
      #pragma unroll
      for (int nt = 0; nt < 2; ++nt)
        #pragma unroll
        for (int r = 0; r < 4; ++r)
          dst[(wt * 16 + quad * 4 + r) * 33 + nt * 16 + l16] = accO[wt][nt][r];
    if (quad == 0) {
      #pragma unroll
      for (int nt = 0; nt < 2; ++nt)
        Ll[qh * 32 + nt * 16 + l16] = l_lane[nt];
    }
  }
  __syncthreads();
  if (th == 0) {
    const float* src = Lo + qh * (64 * 33);
    float l_tot[2];
    #pragma unroll
    for (int nt = 0; nt < 2; ++nt)
      l_tot[nt] = l_lane[nt] + Ll[qh * 32 + nt * 16 + l16];
    #pragma unroll
    for (int wt = 0; wt < 4; ++wt)
      #pragma unroll
      for (int nt = 0; nt < 2; ++nt) {
        floatx4 o;
        #pragma unroll
        for (int r = 0; r < 4; ++r)
          o[r] = (accO[wt][nt][r] +
                  src[(wt * 16 + quad * 4 + r) * 33 + nt * 16 + l16]) / l_tot[nt];
        int row = q0 + qh * 32 + nt * 16 + l16;
        int col = qcol + wt * 16 + quad * 4;
        *reinterpret_cast<floatx4*>(&out[row * D + col]) = o;
      }
  }
}

} // namespace

extern "C" void kernel_launch(void* const* d_in, const int* in_sizes, int n_in,
                              void* d_out, int out_size, void* d_ws, size_t ws_size,
                              hipStream_t stream) {
  const float *x = nullptr, *mask = nullptr, *Wq = nullptr, *bq = nullptr;
  for (int i = 0; i < n_in; ++i) {
    switch (in_sizes[i]) {
      case 3145728: x    = (const float*)d_in[i]; break;
      case 4096:    mask = (const float*)d_in[i]; break;
      case 1769472: Wq   = (const float*)d_in[i]; break;
      case 2304:    bq   = (const float*)d_in[i]; break;
      default: break;
    }
  }

  __bf16* xb = (__bf16*)d_out;               // bf16 scratch in d_out
  __bf16* WT = xb + (size_t)S * D;
  __bf16* Qb = (__bf16*)d_ws;
  __bf16* Kb = Qb + (size_t)S * D;
  __bf16* vT = Kb + (size_t)S * D;

  convert_x <<<(S * D) / 1024, 256, 0, stream>>>(x, xb);
  convert_wt<<<dim3(D / 64, N3 / 64), 256, 0, stream>>>(Wq, WT);
  qkv_gemm  <<<dim3(S / 128, N3 / 128), 256, 0, stream>>>(xb, WT, bq, Qb, Kb, vT);
  attention <<<dim3(S / 64, H), 256, 0, stream>>>(Qb, Kb, vT, mask, (float*)d_out);
}

// Round 18
// 193.241 us; speedup vs baseline: 1.2992x; 1.0798x over previous
//
#include <hip/hip_runtime.h>
#include <hip/hip_bf16.h>

namespace {
constexpr int S  = 4096;
constexpr int D  = 768;
constexpr int H  = 12;
constexpr int N3 = 2304;   // 3*D

typedef __bf16 bf16x4 __attribute__((ext_vector_type(4)));
typedef __bf16 bf16x8 __attribute__((ext_vector_type(8)));
typedef float  floatx4 __attribute__((ext_vector_type(4)));

// async global->LDS, 16B per lane; LDS dest = wave-uniform base + lane*16.
__device__ inline void glds16(const __bf16* g, __bf16* l) {
  __builtin_amdgcn_global_load_lds(
      (const __attribute__((address_space(1))) void*)(const void*)g,
      (__attribute__((address_space(3))) void*)(void*)l, 16, 0, 0);
}

// ---------------------------------------------------------------------------
// Kernel 0: merged converts. bid < 3072: x fp32 -> bf16 (1024 elems/block).
// Else: W [768][2304] fp32 -> WT [2304][768] bf16 via LDS tile transpose.
// ---------------------------------------------------------------------------
__global__ __launch_bounds__(256)
void convert_all(const float* __restrict__ x, __bf16* __restrict__ xb,
                 const float* __restrict__ W, __bf16* __restrict__ WT)
{
  const int bid = blockIdx.x;
  const int tid = threadIdx.x;
  if (bid < 3072) {
    const int i = (bid * 256 + tid) * 4;
    floatx4 v = *reinterpret_cast<const floatx4*>(x + i);
    bf16x4 b;
    #pragma unroll
    for (int e = 0; e < 4; ++e) b[e] = (__bf16)v[e];
    *reinterpret_cast<bf16x4*>(xb + i) = b;
  } else {
    __shared__ float T[64][65];
    const int b2 = bid - 3072;
    const int d0 = (b2 % 12) * 64, e0 = (b2 / 12) * 64;
    const int rr = tid >> 4, c4 = (tid & 15) * 4;
    #pragma unroll
    for (int it = 0; it < 4; ++it) {
      int d = it * 16 + rr;
      floatx4 v = *reinterpret_cast<const floatx4*>(W + (d0 + d) * N3 + e0 + c4);
      #pragma unroll
      for (int e = 0; e < 4; ++e) T[d][c4 + e] = v[e];
    }
    __syncthreads();
    #pragma unroll
    for (int it = 0; it < 4; ++it) {
      int e = it * 16 + rr;
      bf16x4 b;
      #pragma unroll
      for (int i = 0; i < 4; ++i) b[i] = (__bf16)T[c4 + i][e];
      *reinterpret_cast<bf16x4*>(WT + (e0 + e) * D + d0 + c4) = b;
    }
  }
}

// ---------------------------------------------------------------------------
// Kernel 1: QKV GEMM, 128x96 tile -> grid 32x24 = 768 blocks = EXACTLY 3/CU
// (balanced; 576-block 128x128 version had 2.25 generations -> ~33% tail).
// Mainloop: glds16 + XOR swizzle, BK=64. Epilogue: Q/K direct; V via
// swizzled-LDS transpose (k-slot-permuted) then coalesced 16B vT stores.
// ---------------------------------------------------------------------------
__global__ __launch_bounds__(256)
void qkv_gemm(const __bf16* __restrict__ xb, const __bf16* __restrict__ WT,
              const float* __restrict__ bq, __bf16* __restrict__ Qb,
              __bf16* __restrict__ Kb, __bf16* __restrict__ vT)
{
  __shared__ __bf16 smem[14336];           // 28 KB: As(16K) | Bs(12K); vts(24K)
  __bf16* As = smem;                        // [128][64] swizzled
  __bf16* Bs = smem + 8192;                 // [96][64]  swizzled

  const int tid  = threadIdx.x;
  const int wave = tid >> 6, lane = tid & 63;
  const int quad = lane >> 4, l16 = lane & 15;
  const int m_base = (wave >> 1) * 64;
  const int n_base = (wave & 1) * 48;
  const int bm = blockIdx.x, bn = blockIdx.y;
  const int srow = lane >> 3, sg = lane & 7;

  floatx4 acc[4][3];
  #pragma unroll
  for (int i = 0; i < 4; ++i)
    #pragma unroll
    for (int j = 0; j < 3; ++j) acc[i][j] = (floatx4){0.f, 0.f, 0.f, 0.f};

  for (int ks = 0; ks < 12; ++ks) {
    const int k0 = ks * 64;
    __syncthreads();
    #pragma unroll
    for (int it = 0; it < 4; ++it) {           // A: 128 rows
      int rbase = it * 32 + wave * 8;
      int row = rbase + srow;
      glds16(xb + (size_t)(bm * 128 + row) * D + k0 + (sg ^ (row & 7)) * 8,
             As + rbase * 64);
    }
    #pragma unroll
    for (int it = 0; it < 3; ++it) {           // B: 96 rows (exactly covered)
      int rbase = it * 32 + wave * 8;
      int row = rbase + srow;
      glds16(WT + (size_t)(bn * 96 + row) * D + k0 + (sg ^ (row & 7)) * 8,
             Bs + rbase * 64);
    }
    __syncthreads();

    bf16x8 af[4][2], bfr[3][2];
    #pragma unroll
    for (int mt = 0; mt < 4; ++mt)
      #pragma unroll
      for (int kt = 0; kt < 2; ++kt) {
        int m = m_base + mt * 16 + l16;
        af[mt][kt] = *reinterpret_cast<const bf16x8*>(
            &As[m * 64 + ((((kt << 2) | quad) ^ (l16 & 7)) << 3)]);
      }
    #pragma unroll
    for (int nt = 0; nt < 3; ++nt)
      #pragma unroll
      for (int kt = 0; kt < 2; ++kt) {
        int n = n_base + nt * 16 + l16;
        bfr[nt][kt] = *reinterpret_cast<const bf16x8*>(
            &Bs[n * 64 + ((((kt << 2) | quad) ^ (l16 & 7)) << 3)]);
      }
    #pragma unroll
    for (int kt = 0; kt < 2; ++kt)
      #pragma unroll
      for (int mt = 0; mt < 4; ++mt)
        #pragma unroll
        for (int nt = 0; nt < 3; ++nt)
          acc[mt][nt] = __builtin_amdgcn_mfma_f32_16x16x32_bf16(
              af[mt][kt], bfr[nt][kt], acc[mt][nt], 0, 0, 0);
  }

  if (bn < 16) {
    // Q (bn<8) / K: direct stores (4x32B segments per instr).
    #pragma unroll
    for (int nt = 0; nt < 3; ++nt) {
      int col = bn * 96 + n_base + nt * 16 + l16;
      float bias = bq[col];
      #pragma unroll
      for (int mt = 0; mt < 4; ++mt) {
        int row = bm * 128 + m_base + mt * 16 + quad * 4;
        #pragma unroll
        for (int r = 0; r < 4; ++r) {
          __bf16 v = (__bf16)(acc[mt][nt][r] + bias);
          if (bn < 8) Qb[(row + r) * D + col] = v;
          else        Kb[(row + r) * D + (col - D)] = v;
        }
      }
    }
  } else {
    // V: swizzled LDS transpose (k-slot-permuted) -> coalesced vT stores.
    __syncthreads();
    __bf16* vts = smem;   // [w 96][t 128], addr = w*128 + (pos ^ ((w&7)<<3))
    #pragma unroll
    for (int nt = 0; nt < 3; ++nt) {
      int wl = n_base + nt * 16 + l16;          // 0..95 within tile
      float bias = bq[bn * 96 + wl];
      int sw = (wl & 7) << 3;
      #pragma unroll
      for (int mt = 0; mt < 4; ++mt) {
        #pragma unroll
        for (int r = 0; r < 4; ++r) {
          int tl = m_base + mt * 16 + quad * 4 + r;
          int pos = (tl & ~31) | (quad << 3) | ((tl & 16) >> 2) | r;
          vts[wl * 128 + (pos ^ sw)] = (__bf16)(acc[mt][nt][r] + bias);
        }
      }
    }
    __syncthreads();
    const int w0g = bn * 96 - 2 * D;
    #pragma unroll
    for (int it = 0; it < 6; ++it) {            // 96*16 = 1536 chunks
      int c = it * 256 + tid;
      int wl = c >> 4, t0 = (c & 15) * 8;
      bf16x8 v = *reinterpret_cast<const bf16x8*>(
          &vts[wl * 128 + (t0 ^ ((wl & 7) << 3))]);
      *reinterpret_cast<bf16x8*>(
          &vT[(size_t)(w0g + wl) * S + bm * 128 + t0]) = v;
    }
  }
}

// ---------------------------------------------------------------------------
// Kernel 2 (VERBATIM R15/R17, measured 113.4 us): flash attention,
// P-in-registers, wave = 32q x 64t, K via global_load_lds + XOR swizzle,
// V fragments single b128 from k-slot-permuted vT.
// ---------------------------------------------------------------------------
__global__ __launch_bounds__(256)
void attention(const __bf16* __restrict__ Qb, const __bf16* __restrict__ Kb,
               const __bf16* __restrict__ vT, const float* __restrict__ mask,
               float* __restrict__ out)
{
  __shared__ char smem[16384 + 17408 + 256];
  __bf16* Ks = (__bf16*)smem;                        // [128][64], swizzled
  __bf16* Vt = (__bf16*)(smem + 16384);              // [64][136], permuted-t
  float*  Ll = (float*)(smem + 16384 + 17408);       // l partials (64 floats)
  float*  Lo = (float*)smem;                         // alias, end-reduction only

  const int tid  = threadIdx.x;
  const int wave = tid >> 6, lane = tid & 63;
  const int quad = lane >> 4, l16 = lane & 15;
  const int qh = wave >> 1;       // q-half
  const int th = wave & 1;        // t-half
  const int qb = blockIdx.x, h = blockIdx.y;
  const int q0 = qb * 64;
  const int qcol = h * 64;
  const int srow = lane >> 3, sg = lane & 7;

  bf16x8 qf[2][2];
  #pragma unroll
  for (int nt = 0; nt < 2; ++nt)
    #pragma unroll
    for (int kt = 0; kt < 2; ++kt)
      qf[nt][kt] = *reinterpret_cast<const bf16x8*>(
          Qb + (q0 + qh * 32 + nt * 16 + l16) * D + qcol + kt * 32 + quad * 8);

  floatx4 accO[4][2];
  #pragma unroll
  for (int wt = 0; wt < 4; ++wt)
    #pragma unroll
    for (int nt = 0; nt < 2; ++nt) accO[wt][nt] = (floatx4){0.f, 0.f, 0.f, 0.f};
  float l_lane[2] = {0.f, 0.f};

  for (int j = 0; j < 32; ++j) {
    __syncthreads();
    #pragma unroll
    for (int it = 0; it < 4; ++it) {
      int rbase = it * 32 + wave * 8;
      int t = rbase + srow;
      int g = sg ^ (t & 7);
      glds16(Kb + (size_t)(j * 128 + t) * D + qcol + g * 8, Ks + rbase * 64);
    }
    #pragma unroll
    for (int it = 0; it < 4; ++it) {
      int c = it * 256 + tid;
      int w = c >> 4, t0 = (c & 15) * 8;
      *reinterpret_cast<bf16x8*>(&Vt[w * 136 + t0]) =
          *reinterpret_cast<const bf16x8*>(vT + (size_t)(qcol + w) * S + j * 128 + t0);
    }
    __syncthreads();

    bf16x4 ps[4][2];
    #pragma unroll
    for (int mt = 0; mt < 4; ++mt) {
      int trow = th * 64 + mt * 16 + l16;
      bf16x8 kf[2];
      #pragma unroll
      for (int kt = 0; kt < 2; ++kt)
        kf[kt] = *reinterpret_cast<const bf16x8*>(
            &Ks[trow * 64 + ((((kt << 2) | quad) ^ (l16 & 7)) << 3)]);
      floatx4 mv = *reinterpret_cast<const floatx4*>(
          mask + j * 128 + th * 64 + mt * 16 + quad * 4);
      #pragma unroll
      for (int nt = 0; nt < 2; ++nt) {
        floatx4 s = (floatx4){0.f, 0.f, 0.f, 0.f};
        #pragma unroll
        for (int kt = 0; kt < 2; ++kt)
          s = __builtin_amdgcn_mfma_f32_16x16x32_bf16(kf[kt], qf[nt][kt], s, 0, 0, 0);
        #pragma unroll
        for (int r = 0; r < 4; ++r) {
          float p = __expf(s[r] * 0.125f - 10000.f * (1.f - mv[r]));
          l_lane[nt] += p;
          ps[mt][nt][r] = (__bf16)p;
        }
      }
    }

    #pragma unroll
    for (int u = 0; u < 2; ++u) {
      bf16x8 pf[2];
      #pragma unroll
      for (int nt = 0; nt < 2; ++nt)
        #pragma unroll
        for (int r = 0; r < 4; ++r) {
          pf[nt][r]     = ps[2 * u][nt][r];
          pf[nt][4 + r] = ps[2 * u + 1][nt][r];
        }
      #pragma unroll
      for (int wt = 0; wt < 4; ++wt) {
        bf16x8 vf = *reinterpret_cast<const bf16x8*>(
            &Vt[(wt * 16 + l16) * 136 + th * 64 + u * 32 + quad * 8]);
        #pragma unroll
        for (int nt = 0; nt < 2; ++nt)
          accO[wt][nt] = __builtin_amdgcn_mfma_f32_16x16x32_bf16(
              vf, pf[nt], accO[wt][nt], 0, 0, 0);
      }
    }
  }

  #pragma unroll
  for (int nt = 0; nt < 2; ++nt) {
    l_lane[nt] += __shfl_xor(l_lane[nt], 16, 64);
    l_lane[nt] += __shfl_xor(l_lane[nt], 32, 64);
  }
  __syncthreads();
  if (th == 1) {
    float* dst = Lo + qh * (64 * 33);
    #pragma unroll
    for (int wt = 0; wt < 4; ++wt)
      #pragma unroll
      for (int nt = 0; nt < 2; ++nt)
        #pragma unroll
        for (int r = 0; r < 4; ++r)
          dst[(wt * 16 + quad * 4 + r) * 33 + nt * 16 + l16] = accO[wt][nt][r];
    if (quad == 0) {
      #pragma unroll
      for (int nt = 0; nt < 2; ++nt)
        Ll[qh * 32 + nt * 16 + l16] = l_lane[nt];
    }
  }
  __syncthreads();
  if (th == 0) {
    const float* src = Lo + qh * (64 * 33);
    float l_tot[2];
    #pragma unroll
    for (int nt = 0; nt < 2; ++nt)
      l_tot[nt] = l_lane[nt] + Ll[qh * 32 + nt * 16 + l16];
    #pragma unroll
    for (int wt = 0; wt < 4; ++wt)
      #pragma unroll
      for (int nt = 0; nt < 2; ++nt) {
        floatx4 o;
        #pragma unroll
        for (int r = 0; r < 4; ++r)
          o[r] = (accO[wt][nt][r] +
                  src[(wt * 16 + quad * 4 + r) * 33 + nt * 16 + l16]) / l_tot[nt];
        int row = q0 + qh * 32 + nt * 16 + l16;
        int col = qcol + wt * 16 + quad * 4;
        *reinterpret_cast<floatx4*>(&out[row * D + col]) = o;
      }
  }
}

} // namespace

extern "C" void kernel_launch(void* const* d_in, const int* in_sizes, int n_in,
                              void* d_out, int out_size, void* d_ws, size_t ws_size,
                              hipStream_t stream) {
  const float *x = nullptr, *mask = nullptr, *Wq = nullptr, *bq = nullptr;
  for (int i = 0; i < n_in; ++i) {
    switch (in_sizes[i]) {
      case 3145728: x    = (const float*)d_in[i]; break;
      case 4096:    mask = (const float*)d_in[i]; break;
      case 1769472: Wq   = (const float*)d_in[i]; break;
      case 2304:    bq   = (const float*)d_in[i]; break;
      default: break;
    }
  }

  __bf16* xb = (__bf16*)d_out;               // bf16 scratch in d_out
  __bf16* WT = xb + (size_t)S * D;
  __bf16* Qb = (__bf16*)d_ws;
  __bf16* Kb = Qb + (size_t)S * D;
  __bf16* vT = Kb + (size_t)S * D;

  convert_all<<<3072 + 432, 256, 0, stream>>>(x, xb, Wq, WT);
  qkv_gemm   <<<dim3(S / 128, N3 / 96), 256, 0, stream>>>(xb, WT, bq, Qb, Kb, vT);
  attention  <<<dim3(S / 64, H), 256, 0, stream>>>(Qb, Kb, vT, mask, (float*)d_out);
}

// Round 19
// 178.546 us; speedup vs baseline: 1.4061x; 1.0823x over previous
//
#include <hip/hip_runtime.h>
#include <hip/hip_bf16.h>

namespace {
constexpr int S  = 4096;
constexpr int D  = 768;
constexpr int H  = 12;
constexpr int N3 = 2304;   // 3*D

typedef __bf16 bf16x4 __attribute__((ext_vector_type(4)));
typedef __bf16 bf16x8 __attribute__((ext_vector_type(8)));
typedef float  floatx4 __attribute__((ext_vector_type(4)));

// async global->LDS, 16B per lane; LDS dest = wave-uniform base + lane*16.
__device__ inline void glds16(const __bf16* g, __bf16* l) {
  __builtin_amdgcn_global_load_lds(
      (const __attribute__((address_space(1))) void*)(const void*)g,
      (__attribute__((address_space(3))) void*)(void*)l, 16, 0, 0);
}

// ---------------------------------------------------------------------------
// Kernel 0: merged converts. bid < 3072: x fp32 -> bf16 (1024 elems/block).
// Else: W [768][2304] fp32 -> WT [2304][768] bf16 via LDS tile transpose.
// ---------------------------------------------------------------------------
__global__ __launch_bounds__(256)
void convert_all(const float* __restrict__ x, __bf16* __restrict__ xb,
                 const float* __restrict__ W, __bf16* __restrict__ WT)
{
  const int bid = blockIdx.x;
  const int tid = threadIdx.x;
  if (bid < 3072) {
    const int i = (bid * 256 + tid) * 4;
    floatx4 v = *reinterpret_cast<const floatx4*>(x + i);
    bf16x4 b;
    #pragma unroll
    for (int e = 0; e < 4; ++e) b[e] = (__bf16)v[e];
    *reinterpret_cast<bf16x4*>(xb + i) = b;
  } else {
    __shared__ float T[64][65];
    const int b2 = bid - 3072;
    const int d0 = (b2 % 12) * 64, e0 = (b2 / 12) * 64;
    const int rr = tid >> 4, c4 = (tid & 15) * 4;
    #pragma unroll
    for (int it = 0; it < 4; ++it) {
      int d = it * 16 + rr;
      floatx4 v = *reinterpret_cast<const floatx4*>(W + (d0 + d) * N3 + e0 + c4);
      #pragma unroll
      for (int e = 0; e < 4; ++e) T[d][c4 + e] = v[e];
    }
    __syncthreads();
    #pragma unroll
    for (int it = 0; it < 4; ++it) {
      int e = it * 16 + rr;
      bf16x4 b;
      #pragma unroll
      for (int i = 0; i < 4; ++i) b[i] = (__bf16)T[c4 + i][e];
      *reinterpret_cast<bf16x4*>(WT + (e0 + e) * D + d0 + c4) = b;
    }
  }
}

// ---------------------------------------------------------------------------
// Kernel 1 (VERBATIM R18): QKV GEMM, 128x96 tile, grid 32x24 = 768 = 3/CU.
// glds16 + XOR swizzle, BK=64. Q/K direct stores; V via swizzled-LDS
// transpose (k-slot-permuted) then coalesced 16B vT stores.
// ---------------------------------------------------------------------------
__global__ __launch_bounds__(256)
void qkv_gemm(const __bf16* __restrict__ xb, const __bf16* __restrict__ WT,
              const float* __restrict__ bq, __bf16* __restrict__ Qb,
              __bf16* __restrict__ Kb, __bf16* __restrict__ vT)
{
  __shared__ __bf16 smem[14336];           // 28 KB: As(16K) | Bs(12K); vts(24K)
  __bf16* As = smem;                        // [128][64] swizzled
  __bf16* Bs = smem + 8192;                 // [96][64]  swizzled

  const int tid  = threadIdx.x;
  const int wave = tid >> 6, lane = tid & 63;
  const int quad = lane >> 4, l16 = lane & 15;
  const int m_base = (wave >> 1) * 64;
  const int n_base = (wave & 1) * 48;
  const int bm = blockIdx.x, bn = blockIdx.y;
  const int srow = lane >> 3, sg = lane & 7;

  floatx4 acc[4][3];
  #pragma unroll
  for (int i = 0; i < 4; ++i)
    #pragma unroll
    for (int j = 0; j < 3; ++j) acc[i][j] = (floatx4){0.f, 0.f, 0.f, 0.f};

  for (int ks = 0; ks < 12; ++ks) {
    const int k0 = ks * 64;
    __syncthreads();
    #pragma unroll
    for (int it = 0; it < 4; ++it) {
      int rbase = it * 32 + wave * 8;
      int row = rbase + srow;
      glds16(xb + (size_t)(bm * 128 + row) * D + k0 + (sg ^ (row & 7)) * 8,
             As + rbase * 64);
    }
    #pragma unroll
    for (int it = 0; it < 3; ++it) {
      int rbase = it * 32 + wave * 8;
      int row = rbase + srow;
      glds16(WT + (size_t)(bn * 96 + row) * D + k0 + (sg ^ (row & 7)) * 8,
             Bs + rbase * 64);
    }
    __syncthreads();

    bf16x8 af[4][2], bfr[3][2];
    #pragma unroll
    for (int mt = 0; mt < 4; ++mt)
      #pragma unroll
      for (int kt = 0; kt < 2; ++kt) {
        int m = m_base + mt * 16 + l16;
        af[mt][kt] = *reinterpret_cast<const bf16x8*>(
            &As[m * 64 + ((((kt << 2) | quad) ^ (l16 & 7)) << 3)]);
      }
    #pragma unroll
    for (int nt = 0; nt < 3; ++nt)
      #pragma unroll
      for (int kt = 0; kt < 2; ++kt) {
        int n = n_base + nt * 16 + l16;
        bfr[nt][kt] = *reinterpret_cast<const bf16x8*>(
            &Bs[n * 64 + ((((kt << 2) | quad) ^ (l16 & 7)) << 3)]);
      }
    #pragma unroll
    for (int kt = 0; kt < 2; ++kt)
      #pragma unroll
      for (int mt = 0; mt < 4; ++mt)
        #pragma unroll
        for (int nt = 0; nt < 3; ++nt)
          acc[mt][nt] = __builtin_amdgcn_mfma_f32_16x16x32_bf16(
              af[mt][kt], bfr[nt][kt], acc[mt][nt], 0, 0, 0);
  }

  if (bn < 16) {
    #pragma unroll
    for (int nt = 0; nt < 3; ++nt) {
      int col = bn * 96 + n_base + nt * 16 + l16;
      float bias = bq[col];
      #pragma unroll
      for (int mt = 0; mt < 4; ++mt) {
        int row = bm * 128 + m_base + mt * 16 + quad * 4;
        #pragma unroll
        for (int r = 0; r < 4; ++r) {
          __bf16 v = (__bf16)(acc[mt][nt][r] + bias);
          if (bn < 8) Qb[(row + r) * D + col] = v;
          else        Kb[(row + r) * D + (col - D)] = v;
        }
      }
    }
  } else {
    __syncthreads();
    __bf16* vts = smem;   // [w 96][t 128], addr = w*128 + (pos ^ ((w&7)<<3))
    #pragma unroll
    for (int nt = 0; nt < 3; ++nt) {
      int wl = n_base + nt * 16 + l16;
      float bias = bq[bn * 96 + wl];
      int sw = (wl & 7) << 3;
      #pragma unroll
      for (int mt = 0; mt < 4; ++mt) {
        #pragma unroll
        for (int r = 0; r < 4; ++r) {
          int tl = m_base + mt * 16 + quad * 4 + r;
          int pos = (tl & ~31) | (quad << 3) | ((tl & 16) >> 2) | r;
          vts[wl * 128 + (pos ^ sw)] = (__bf16)(acc[mt][nt][r] + bias);
        }
      }
    }
    __syncthreads();
    const int w0g = bn * 96 - 2 * D;
    #pragma unroll
    for (int it = 0; it < 6; ++it) {
      int c = it * 256 + tid;
      int wl = c >> 4, t0 = (c & 15) * 8;
      bf16x8 v = *reinterpret_cast<const bf16x8*>(
          &vts[wl * 128 + (t0 ^ ((wl & 7) << 3))]);
      *reinterpret_cast<bf16x8*>(
          &vT[(size_t)(w0g + wl) * S + bm * 128 + t0]) = v;
    }
  }
}

// ---------------------------------------------------------------------------
// Kernel 2: flash attention, R15/R18 shape (wave = 32q x 64t, P-in-registers).
// ONLY CHANGE: V also staged via global_load_lds into an unpadded swizzled
// [64][128] tile (mechanism validated in R16) — removes the last VGPR
// round-trip (4 global loads + 4 ds_writes per thread/step).
// ---------------------------------------------------------------------------
__global__ __launch_bounds__(256)
void attention(const __bf16* __restrict__ Qb, const __bf16* __restrict__ Kb,
               const __bf16* __restrict__ vT, const float* __restrict__ mask,
               float* __restrict__ out)
{
  __shared__ char smem[16384 + 16384 + 256];
  __bf16* Ks = (__bf16*)smem;                 // [128][64], swizzled
  __bf16* Vt = (__bf16*)(smem + 16384);       // [64][128], swizzled + permuted-t
  float*  Ll = (float*)(smem + 32768);        // l partials (64 floats)
  float*  Lo = (float*)smem;                  // alias, end-reduction only

  const int tid  = threadIdx.x;
  const int wave = tid >> 6, lane = tid & 63;
  const int quad = lane >> 4, l16 = lane & 15;
  const int qh = wave >> 1;       // q-half
  const int th = wave & 1;        // t-half
  const int qb = blockIdx.x, h = blockIdx.y;
  const int q0 = qb * 64;
  const int qcol = h * 64;
  const int srow = lane >> 3, sg = lane & 7;
  const int vrow = lane >> 4, vs = lane & 15;

  bf16x8 qf[2][2];
  #pragma unroll
  for (int nt = 0; nt < 2; ++nt)
    #pragma unroll
    for (int kt = 0; kt < 2; ++kt)
      qf[nt][kt] = *reinterpret_cast<const bf16x8*>(
          Qb + (q0 + qh * 32 + nt * 16 + l16) * D + qcol + kt * 32 + quad * 8);

  floatx4 accO[4][2];
  #pragma unroll
  for (int wt = 0; wt < 4; ++wt)
    #pragma unroll
    for (int nt = 0; nt < 2; ++nt) accO[wt][nt] = (floatx4){0.f, 0.f, 0.f, 0.f};
  float l_lane[2] = {0.f, 0.f};

  for (int j = 0; j < 32; ++j) {
    __syncthreads();
    // K tile 128x64 + V tile 64x128, both via async DMA with XOR swizzle.
    #pragma unroll
    for (int it = 0; it < 4; ++it) {
      int rbase = it * 32 + wave * 8;
      int t = rbase + srow;
      glds16(Kb + (size_t)(j * 128 + t) * D + qcol + (sg ^ (t & 7)) * 8,
             Ks + rbase * 64);
      int wbase = it * 16 + wave * 4;
      int w = wbase + vrow;
      glds16(vT + (size_t)(qcol + w) * S + j * 128 + (vs ^ (w & 7)) * 8,
             Vt + wbase * 128);
    }
    __syncthreads();

    // S^T = K Q^T ; P = exp(...) in-register.
    bf16x4 ps[4][2];
    #pragma unroll
    for (int mt = 0; mt < 4; ++mt) {
      int trow = th * 64 + mt * 16 + l16;
      bf16x8 kf[2];
      #pragma unroll
      for (int kt = 0; kt < 2; ++kt)
        kf[kt] = *reinterpret_cast<const bf16x8*>(
            &Ks[trow * 64 + ((((kt << 2) | quad) ^ (l16 & 7)) << 3)]);
      floatx4 mv = *reinterpret_cast<const floatx4*>(
          mask + j * 128 + th * 64 + mt * 16 + quad * 4);
      #pragma unroll
      for (int nt = 0; nt < 2; ++nt) {
        floatx4 s = (floatx4){0.f, 0.f, 0.f, 0.f};
        #pragma unroll
        for (int kt = 0; kt < 2; ++kt)
          s = __builtin_amdgcn_mfma_f32_16x16x32_bf16(kf[kt], qf[nt][kt], s, 0, 0, 0);
        #pragma unroll
        for (int r = 0; r < 4; ++r) {
          float p = __expf(s[r] * 0.125f - 10000.f * (1.f - mv[r]));
          l_lane[nt] += p;
          ps[mt][nt][r] = (__bf16)p;
        }
      }
    }

    // O^T += V^T P^T : vf ONE b128 from swizzled slot, pf register concat.
    #pragma unroll
    for (int u = 0; u < 2; ++u) {
      bf16x8 pf[2];
      #pragma unroll
      for (int nt = 0; nt < 2; ++nt)
        #pragma unroll
        for (int r = 0; r < 4; ++r) {
          pf[nt][r]     = ps[2 * u][nt][r];
          pf[nt][4 + r] = ps[2 * u + 1][nt][r];
        }
      #pragma unroll
      for (int wt = 0; wt < 4; ++wt) {
        int w = wt * 16 + l16;
        bf16x8 vf = *reinterpret_cast<const bf16x8*>(
            &Vt[w * 128 + (((th * 8 + u * 4 + quad) ^ (w & 7)) << 3)]);
        #pragma unroll
        for (int nt = 0; nt < 2; ++nt)
          accO[wt][nt] = __builtin_amdgcn_mfma_f32_16x16x32_bf16(
              vf, pf[nt], accO[wt][nt], 0, 0, 0);
      }
    }
  }

  // ---- cross-wave reduction over t-halves ----
  #pragma unroll
  for (int nt = 0; nt < 2; ++nt) {
    l_lane[nt] += __shfl_xor(l_lane[nt], 16, 64);
    l_lane[nt] += __shfl_xor(l_lane[nt], 32, 64);
  }
  __syncthreads();   // all Ks/Vt reads done; safe to alias Lo
  if (th == 1) {
    float* dst = Lo + qh * (64 * 33);
    #pragma unroll
    for (int wt = 0; wt < 4; ++wt)
      #pragma unroll
      for (int nt = 0; nt < 2; ++nt)
        #pragma unroll
        for (int r = 0; r < 4; ++r)
          dst[(wt * 16 + quad * 4 + r) * 33 + nt * 16 + l16] = accO[wt][nt][r];
    if (quad == 0) {
      #pragma unroll
      for (int nt = 0; nt < 2; ++nt)
        Ll[qh * 32 + nt * 16 + l16] = l_lane[nt];
    }
  }
  __syncthreads();
  if (th == 0) {
    const float* src = Lo + qh * (64 * 33);
    float l_tot[2];
    #pragma unroll
    for (int nt = 0; nt < 2; ++nt)
      l_tot[nt] = l_lane[nt] + Ll[qh * 32 + nt * 16 + l16];
    #pragma unroll
    for (int wt = 0; wt < 4; ++wt)
      #pragma unroll
      for (int nt = 0; nt < 2; ++nt) {
        floatx4 o;
        #pragma unroll
        for (int r = 0; r < 4; ++r)
          o[r] = (accO[wt][nt][r] +
                  src[(wt * 16 + quad * 4 + r) * 33 + nt * 16 + l16]) / l_tot[nt];
        int row = q0 + qh * 32 + nt * 16 + l16;
        int col = qcol + wt * 16 + quad * 4;
        *reinterpret_cast<floatx4*>(&out[row * D + col]) = o;
      }
  }
}

} // namespace

extern "C" void kernel_launch(void* const* d_in, const int* in_sizes, int n_in,
                              void* d_out, int out_size, void* d_ws, size_t ws_size,
                              hipStream_t stream) {
  const float *x = nullptr, *mask = nullptr, *Wq = nullptr, *bq = nullptr;
  for (int i = 0; i < n_in; ++i) {
    switch (in_sizes[i]) {
      case 3145728: x    = (const float*)d_in[i]; break;
      case 4096:    mask = (const float*)d_in[i]; break;
      case 1769472: Wq   = (const float*)d_in[i]; break;
      case 2304:    bq   = (const float*)d_in[i]; break;
      default: break;
    }
  }

  __bf16* xb = (__bf16*)d_out;               // bf16 scratch in d_out
  __bf16* WT = xb + (size_t)S * D;
  __bf16* Qb = (__bf16*)d_ws;
  __bf16* Kb = Qb + (size_t)S * D;
  __bf16* vT = Kb + (size_t)S * D;

  convert_all<<<3072 + 432, 256, 0, stream>>>(x, xb, Wq, WT);
  qkv_gemm   <<<dim3(S / 128, N3 / 96), 256, 0, stream>>>(xb, WT, bq, Qb, Kb, vT);
  attention  <<<dim3(S / 64, H), 256, 0, stream>>>(Qb, Kb, vT, mask, (float*)d_out);
}